// Round 2
// baseline (266.905 us; speedup 1.0000x reference)
//
#include <hip/hip_runtime.h>
#include <hip/hip_bf16.h>

typedef __attribute__((ext_vector_type(8))) short short8;
typedef __attribute__((ext_vector_type(4))) float f32x4;
typedef unsigned short u16;
typedef unsigned int u32;
typedef unsigned long long u64;

typedef u64    __attribute__((may_alias)) u64a;
typedef short8 __attribute__((may_alias)) short8a;
typedef float4 __attribute__((may_alias)) float4a;

#define Tseq 4096
#define LPP  72

__device__ __forceinline__ u32 pk_bf(float a, float b) {
    union { __hip_bfloat162 h; u32 u; } t;
    float2 f; f.x = a; f.y = b;
    t.h = __float22bfloat162_rn(f);
    return t.u;
}

__device__ __forceinline__ u16 f2bf(float f) {
    u32 u = __float_as_uint(f);
    u = (u + 0x7FFFu + ((u >> 16) & 1u)) >> 16;
    return (u16)u;
}

__device__ __forceinline__ short8 ld_frag_lds(const u16* p) {
    union { short8 v; u64 u[2]; } t;
    t.u[0] = *(const u64a*)(p);
    t.u[1] = *(const u64a*)(p + 4);
    return t.v;
}

__device__ __forceinline__ short8 cvt8(float4 a, float4 b) {
    union { short8 s; u32 u[4]; } t;
    t.u[0] = pk_bf(a.x, a.y); t.u[1] = pk_bf(a.z, a.w);
    t.u[2] = pk_bf(b.x, b.y); t.u[3] = pk_bf(b.z, b.w);
    return t.s;
}

__device__ __forceinline__ void gld_lds16(const void* g, void* l) {
    __builtin_amdgcn_global_load_lds(
        (const __attribute__((address_space(1))) u32*)g,
        (__attribute__((address_space(3))) u32*)l, 16, 0, 0);
}

// ---- W -> fragment-major bf16 (B-operand layout), 1/sqrt(C) folded into Wq ----
__global__ __launch_bounds__(256) void wt_kernel(const float* __restrict__ Wq,
                                                 const float* __restrict__ Wk,
                                                 const float* __restrict__ Wv,
                                                 u16* __restrict__ wtf) {
    int idx = blockIdx.x * 256 + threadIdx.x;
    int lane = idx & 63, cc = (idx >> 6) & 31, n = (idx >> 11) & 3, mat = idx >> 13;
    const float* W = (mat == 0) ? Wq : ((mat == 1) ? Wk : Wv);
    float sc = (mat == 0) ? 0.03125f : 1.0f;
    int h = n * 16 + (lane & 15);
    int cbase = cc * 32 + (lane >> 4) * 8;
    union { short8 s; u32 u[4]; } t;
#pragma unroll
    for (int j2 = 0; j2 < 4; ++j2) {
        float a = W[(size_t)(cbase + j2 * 2)     * 64 + h] * sc;
        float b = W[(size_t)(cbase + j2 * 2 + 1) * 64 + h] * sc;
        t.u[j2] = pk_bf(a, b);
    }
    *(short8a*)(wtf + (size_t)idx * 8) = t.s;
}

// ---- QKV projection: async-LDS W staging (double-buffered), x reg pipeline ----
__global__ __launch_bounds__(256, 2) void proj_kernel(const float* __restrict__ x,
                                                      const u16* __restrict__ wtf,
                                                      u16* __restrict__ qb,
                                                      u16* __restrict__ kA,
                                                      u16* __restrict__ vA) {
    // phase = 2 cc's; buf = 12 mn x 2 ccp x 64 lanes x 8 u16 = 24 KiB
    __shared__ __align__(16) u16 Wl[2][12 * 2 * 64 * 8];

    const int tid = threadIdx.x, lane = tid & 63, wave = tid >> 6;
    const int m = lane & 15, quad = lane >> 4;
    const long rowbase = (long)blockIdx.x * 64 + wave * 16;
    const float* xr = x + (rowbase + m) * 1024 + quad * 8;

    f32x4 acc[12];
#pragma unroll
    for (int i = 0; i < 12; ++i) acc[i] = (f32x4){0.f, 0.f, 0.f, 0.f};

    // stage phase p into Wl[buf]: 24 chunks of 1 KiB; this wave does 6
#define STAGE(p, buf)                                                          \
    {                                                                          \
        _Pragma("unroll")                                                      \
        for (int i = 0; i < 6; ++i) {                                          \
            int c = wave * 6 + i, mn = c >> 1, ccp = c & 1;                    \
            const u16* g = wtf + ((size_t)(mn * 32 + (p) * 2 + ccp) * 64 + lane) * 8; \
            u16* l = &Wl[buf][(size_t)(mn * 2 + ccp) * 512];                   \
            gld_lds16(g, l);                                                   \
        }                                                                      \
    }

    float4 xa[4], xb[4];
#pragma unroll
    for (int t = 0; t < 4; ++t)
        xa[t] = *(const float4a*)(xr + (t >> 1) * 32 + (t & 1) * 4);
#pragma unroll
    for (int t = 0; t < 4; ++t)
        xb[t] = *(const float4a*)(xr + (2 + (t >> 1)) * 32 + (t & 1) * 4);

    STAGE(0, 0);
    __syncthreads();

    for (int p = 0; p < 16; ++p) {
        if (p < 15) STAGE(p + 1, (p + 1) & 1);
        float4 xn[4];
        if (p < 14) {
#pragma unroll
            for (int t = 0; t < 4; ++t)
                xn[t] = *(const float4a*)(xr + (2 * (p + 2) + (t >> 1)) * 32 + (t & 1) * 4);
        }
        const u16* wb = Wl[p & 1];
#pragma unroll
        for (int ccp = 0; ccp < 2; ++ccp) {
            short8 af = cvt8(xa[ccp * 2], xa[ccp * 2 + 1]);
#pragma unroll
            for (int mn = 0; mn < 12; ++mn) {
                short8 bf = *(const short8a*)(wb + ((size_t)(mn * 2 + ccp) * 64 + lane) * 8);
                acc[mn] = __builtin_amdgcn_mfma_f32_16x16x32_bf16(af, bf, acc[mn], 0, 0, 0);
            }
        }
#pragma unroll
        for (int t = 0; t < 4; ++t) { xa[t] = xb[t]; if (p < 14) xb[t] = xn[t]; }
        __syncthreads();
    }
#undef STAGE

    const int b  = (int)(rowbase >> 12);
    const int tb = (int)(rowbase & 4095);

    // q: natural [t][h]
#pragma unroll
    for (int n = 0; n < 4; ++n)
#pragma unroll
        for (int r = 0; r < 4; ++r)
            qb[(rowbase + quad * 4 + r) * 64 + n * 16 + m] = f2bf(acc[n][r]);

    // kA[b][key>>4][h>>5][(key&15)+16*((h>>3)&3)][h&7]
#pragma unroll
    for (int n = 0; n < 4; ++n) {
        int kk = n >> 1;
        int lq = (n * 2 + (m >> 3)) & 3;
        int j  = m & 7;
#pragma unroll
        for (int r = 0; r < 4; ++r) {
            int key = tb + quad * 4 + r;
            size_t a = ((((size_t)b * 256 + (key >> 4)) * 2 + kk) * 64
                        + ((key & 15) + 16 * lq)) * 8 + j;
            kA[a] = f2bf(acc[4 + n][r]);
        }
    }

    // vA[b][h>>4][key>>5][(h&15)+16*((key>>3)&3)][key&7]
    {
        int key0 = tb + quad * 4;
        int j0 = key0 & 7;
        int q2 = (key0 >> 3) & 3;
        int kc = key0 >> 5;
#pragma unroll
        for (int n = 0; n < 4; ++n) {
            u64 pv = (u64)pk_bf(acc[8 + n][0], acc[8 + n][1])
                   | ((u64)pk_bf(acc[8 + n][2], acc[8 + n][3]) << 32);
            size_t a = ((((size_t)b * 4 + n) * 128 + kc) * 64 + (m + 16 * q2)) * 8 + j0;
            *(u64a*)(vA + a) = pv;
        }
    }
}

// ---- attention: 64-row blocks, K/V staged once per block into LDS (dbuf) ----
// Block = strips 4g..4g+3 (one per wave); all share diagonal tile n_s = g, so
// all 4 waves walk kt = 0..g in lockstep. Each wave owns its strip end-to-end:
// no split-K, no merge. K/V tiles are contiguous per-kt in kA/vA, staged
// linearly so the in-LDS byte layout equals the verified fragment layout.
__global__ __launch_bounds__(256, 2) void attn_kernel(const u16* __restrict__ qb,
                                                      const u16* __restrict__ kA,
                                                      const u16* __restrict__ vA,
                                                      float* __restrict__ out) {
    __shared__ __align__(16) u16 KVl[2][2][4096];   // [buf][K/V][8 KiB]
    __shared__ __align__(16) u16 Pt[4][16 * LPP];

    const int tid = threadIdx.x, lane = tid & 63, wave = tid >> 6;
    const int m = lane & 15, quad = lane >> 4;
    const int beta = blockIdx.x;
    const int b = beta & 7;                 // XCD affinity: one batch per XCD
    const int u = beta >> 3;                // 0..63
    // heavy blocks dispatch first; CU pair (u, u+32) sums to 65 steps
    const int g = (u < 32) ? (63 - u) : (u - 32);

    const int qbase = (g * 4 + wave) * 16;
    const int qrow = qbase + m;

    const u16* qp = qb + ((size_t)b * Tseq + qbase + m) * 64;
    short8 qf0 = *(const short8a*)(qp + quad * 8);
    short8 qf1 = *(const short8a*)(qp + 32 + quad * 8);

    const u16* kAb = kA + (size_t)b * (256 * 2 * 64 * 8);
    const u16* vAb = vA + (size_t)b * (4 * 128 * 64 * 8);
    u16* pw = Pt[wave];

    f32x4 o0 = {0.f, 0.f, 0.f, 0.f}, o1 = o0, o2 = o0, o3 = o0;
    float lsum = 0.f;

    const float L2E = 1.4426950408889634f;
    const float FMB = 4.0f * L2E;

    // stage tile kt into KVl[bf]: 16 chunks of 1 KiB; waves 0-1 do K, 2-3 do V
#define ASTAGE(kt, bf)                                                         \
    {                                                                          \
        if (wave < 2) {                                                        \
            _Pragma("unroll")                                                  \
            for (int i = 0; i < 4; ++i) {                                      \
                int c = wave * 4 + i;                                          \
                const u16* gp = kAb + (size_t)(kt) * 4096 + c * 512 + lane * 8;\
                gld_lds16(gp, &KVl[bf][0][c * 512]);                           \
            }                                                                  \
        } else {                                                               \
            _Pragma("unroll")                                                  \
            for (int i = 0; i < 4; ++i) {                                      \
                int j = (wave - 2) * 4 + i, ht = j >> 1, hf = j & 1;           \
                const u16* gp = vAb + (size_t)(kt) * 1024 + (size_t)ht * 65536 \
                                + hf * 512 + lane * 8;                         \
                gld_lds16(gp, &KVl[bf][1][ht * 1024 + hf * 512]);              \
            }                                                                  \
        }                                                                      \
    }

    ASTAGE(0, 0);
    __syncthreads();

    int buf = 0;
    for (int kt = 0; kt <= g; ++kt) {
        if (kt < g) ASTAGE(kt + 1, buf ^ 1);

        const u16* Klb = KVl[buf][0];
        const u16* Vlb = KVl[buf][1];

        // V frags early (independent of S chain)
        short8 vf[8];
#pragma unroll
        for (int ht = 0; ht < 4; ++ht) {
            vf[ht * 2]     = *(const short8a*)(Vlb + ht * 1024 + lane * 8);
            vf[ht * 2 + 1] = *(const short8a*)(Vlb + ht * 1024 + 512 + lane * 8);
        }

        f32x4 s[4];
#pragma unroll
        for (int mt = 0; mt < 4; ++mt) {
            short8 kf0 = *(const short8a*)(Klb + mt * 1024 + lane * 8);
            short8 kf1 = *(const short8a*)(Klb + mt * 1024 + 512 + lane * 8);
            f32x4 a = (f32x4){0.f, 0.f, 0.f, 0.f};
            a = __builtin_amdgcn_mfma_f32_16x16x32_bf16(kf0, qf0, a, 0, 0, 0);
            a = __builtin_amdgcn_mfma_f32_16x16x32_bf16(kf1, qf1, a, 0, 0, 0);
            s[mt] = a;
        }

        if (kt == g) {
#pragma unroll
            for (int mt = 0; mt < 4; ++mt)
#pragma unroll
                for (int r = 0; r < 4; ++r) {
                    int key = kt * 64 + mt * 16 + quad * 4 + r;
                    if (key > qrow) s[mt][r] = -1e30f;
                }
        }

#pragma unroll
        for (int mt = 0; mt < 4; ++mt) {
            float p0 = __builtin_amdgcn_exp2f(s[mt][0] * L2E - FMB);
            float p1 = __builtin_amdgcn_exp2f(s[mt][1] * L2E - FMB);
            float p2 = __builtin_amdgcn_exp2f(s[mt][2] * L2E - FMB);
            float p3 = __builtin_amdgcn_exp2f(s[mt][3] * L2E - FMB);
            lsum += (p0 + p1) + (p2 + p3);
            u64 pv = (u64)pk_bf(p0, p1) | ((u64)pk_bf(p2, p3) << 32);
            *(u64a*)(pw + m * LPP + mt * 16 + quad * 4) = pv;
        }
        __builtin_amdgcn_wave_barrier();
        short8 pf0 = ld_frag_lds(pw + m * LPP + quad * 8);
        short8 pf1 = ld_frag_lds(pw + m * LPP + 32 + quad * 8);
        o0 = __builtin_amdgcn_mfma_f32_16x16x32_bf16(vf[0], pf0, o0, 0, 0, 0);
        o0 = __builtin_amdgcn_mfma_f32_16x16x32_bf16(vf[1], pf1, o0, 0, 0, 0);
        o1 = __builtin_amdgcn_mfma_f32_16x16x32_bf16(vf[2], pf0, o1, 0, 0, 0);
        o1 = __builtin_amdgcn_mfma_f32_16x16x32_bf16(vf[3], pf1, o1, 0, 0, 0);
        o2 = __builtin_amdgcn_mfma_f32_16x16x32_bf16(vf[4], pf0, o2, 0, 0, 0);
        o2 = __builtin_amdgcn_mfma_f32_16x16x32_bf16(vf[5], pf1, o2, 0, 0, 0);
        o3 = __builtin_amdgcn_mfma_f32_16x16x32_bf16(vf[6], pf0, o3, 0, 0, 0);
        o3 = __builtin_amdgcn_mfma_f32_16x16x32_bf16(vf[7], pf1, o3, 0, 0, 0);

        __syncthreads();
        buf ^= 1;
    }
#undef ASTAGE

    // every wave finalizes its own strip (no merge)
    lsum += __shfl_xor(lsum, 16, 64);
    lsum += __shfl_xor(lsum, 32, 64);
    float inv = 1.0f / lsum;

    float* orow = out + ((size_t)b * Tseq + qbase + m) * 64;
    float4 w;
    w.x = o0[0] * inv; w.y = o0[1] * inv; w.z = o0[2] * inv; w.w = o0[3] * inv;
    *(float4a*)(orow + 0 * 16 + quad * 4) = w;
    w.x = o1[0] * inv; w.y = o1[1] * inv; w.z = o1[2] * inv; w.w = o1[3] * inv;
    *(float4a*)(orow + 1 * 16 + quad * 4) = w;
    w.x = o2[0] * inv; w.y = o2[1] * inv; w.z = o2[2] * inv; w.w = o2[3] * inv;
    *(float4a*)(orow + 2 * 16 + quad * 4) = w;
    w.x = o3[0] * inv; w.y = o3[1] * inv; w.z = o3[2] * inv; w.w = o3[3] * inv;
    *(float4a*)(orow + 3 * 16 + quad * 4) = w;
}

extern "C" void kernel_launch(void* const* d_in, const int* in_sizes, int n_in,
                              void* d_out, int out_size, void* d_ws, size_t ws_size,
                              hipStream_t stream) {
    const float* x  = (const float*)d_in[0];
    const float* Wq = (const float*)d_in[1];
    const float* Wk = (const float*)d_in[2];
    const float* Wv = (const float*)d_in[3];
    float* out = (float*)d_out;

    char* ws = (char*)d_ws;
    u16* wtf = (u16*)ws;                                       // 384 KiB
    u16* qb  = (u16*)(ws + 512 * 1024);                        // 4 MiB
    u16* kA  = (u16*)(ws + 512 * 1024 + 4 * 1024 * 1024);      // 4 MiB
    u16* vA  = (u16*)(ws + 512 * 1024 + 8 * 1024 * 1024);      // 4 MiB

    wt_kernel<<<96, 256, 0, stream>>>(Wq, Wk, Wv, wtf);
    proj_kernel<<<512, 256, 0, stream>>>(x, wtf, qb, kA, vA);
    attn_kernel<<<512, 256, 0, stream>>>(qb, kA, vA, out);
}

// Round 3
// 239.844 us; speedup vs baseline: 1.1128x; 1.1128x over previous
//
#include <hip/hip_runtime.h>
#include <hip/hip_bf16.h>

typedef __attribute__((ext_vector_type(8))) short short8;
typedef __attribute__((ext_vector_type(4))) float f32x4;
typedef unsigned short u16;
typedef unsigned int u32;
typedef unsigned long long u64;

typedef u64    __attribute__((may_alias)) u64a;
typedef short8 __attribute__((may_alias)) short8a;
typedef float4 __attribute__((may_alias)) float4a;

#define Tseq 4096
#define LPP  72

__device__ __forceinline__ u32 pk_bf(float a, float b) {
    union { __hip_bfloat162 h; u32 u; } t;
    float2 f; f.x = a; f.y = b;
    t.h = __float22bfloat162_rn(f);
    return t.u;
}

__device__ __forceinline__ u16 f2bf(float f) {
    u32 u = __float_as_uint(f);
    u = (u + 0x7FFFu + ((u >> 16) & 1u)) >> 16;
    return (u16)u;
}

__device__ __forceinline__ short8 ld_frag_lds(const u16* p) {
    union { short8 v; u64 u[2]; } t;
    t.u[0] = *(const u64a*)(p);
    t.u[1] = *(const u64a*)(p + 4);
    return t.v;
}

__device__ __forceinline__ short8 cvt8(float4 a, float4 b) {
    union { short8 s; u32 u[4]; } t;
    t.u[0] = pk_bf(a.x, a.y); t.u[1] = pk_bf(a.z, a.w);
    t.u[2] = pk_bf(b.x, b.y); t.u[3] = pk_bf(b.z, b.w);
    return t.s;
}

__device__ __forceinline__ void gld_lds16(const void* g, void* l) {
    __builtin_amdgcn_global_load_lds(
        (const __attribute__((address_space(1))) u32*)g,
        (__attribute__((address_space(3))) u32*)l, 16, 0, 0);
}

// ---- W -> fragment-major bf16 (B-operand layout), 1/sqrt(C) folded into Wq ----
__global__ __launch_bounds__(256) void wt_kernel(const float* __restrict__ Wq,
                                                 const float* __restrict__ Wk,
                                                 const float* __restrict__ Wv,
                                                 u16* __restrict__ wtf) {
    int idx = blockIdx.x * 256 + threadIdx.x;
    int lane = idx & 63, cc = (idx >> 6) & 31, n = (idx >> 11) & 3, mat = idx >> 13;
    const float* W = (mat == 0) ? Wq : ((mat == 1) ? Wk : Wv);
    float sc = (mat == 0) ? 0.03125f : 1.0f;
    int h = n * 16 + (lane & 15);
    int cbase = cc * 32 + (lane >> 4) * 8;
    union { short8 s; u32 u[4]; } t;
#pragma unroll
    for (int j2 = 0; j2 < 4; ++j2) {
        float a = W[(size_t)(cbase + j2 * 2)     * 64 + h] * sc;
        float b = W[(size_t)(cbase + j2 * 2 + 1) * 64 + h] * sc;
        t.u[j2] = pk_bf(a, b);
    }
    *(short8a*)(wtf + (size_t)idx * 8) = t.s;
}

// ---- QKV projection: async-LDS W staging (double-buffered), x reg pipeline ----
__global__ __launch_bounds__(256, 2) void proj_kernel(const float* __restrict__ x,
                                                      const u16* __restrict__ wtf,
                                                      u16* __restrict__ qb,
                                                      u16* __restrict__ kA,
                                                      u16* __restrict__ vA) {
    // phase = 2 cc's; buf = 12 mn x 2 ccp x 64 lanes x 8 u16 = 24 KiB
    __shared__ __align__(16) u16 Wl[2][12 * 2 * 64 * 8];

    const int tid = threadIdx.x, lane = tid & 63, wave = tid >> 6;
    const int m = lane & 15, quad = lane >> 4;
    const long rowbase = (long)blockIdx.x * 64 + wave * 16;
    const float* xr = x + (rowbase + m) * 1024 + quad * 8;

    f32x4 acc[12];
#pragma unroll
    for (int i = 0; i < 12; ++i) acc[i] = (f32x4){0.f, 0.f, 0.f, 0.f};

    // stage phase p into Wl[buf]: 24 chunks of 1 KiB; this wave does 6
#define STAGE(p, buf)                                                          \
    {                                                                          \
        _Pragma("unroll")                                                      \
        for (int i = 0; i < 6; ++i) {                                          \
            int c = wave * 6 + i, mn = c >> 1, ccp = c & 1;                    \
            const u16* g = wtf + ((size_t)(mn * 32 + (p) * 2 + ccp) * 64 + lane) * 8; \
            u16* l = &Wl[buf][(size_t)(mn * 2 + ccp) * 512];                   \
            gld_lds16(g, l);                                                   \
        }                                                                      \
    }

    float4 xa[4], xb[4];
#pragma unroll
    for (int t = 0; t < 4; ++t)
        xa[t] = *(const float4a*)(xr + (t >> 1) * 32 + (t & 1) * 4);
#pragma unroll
    for (int t = 0; t < 4; ++t)
        xb[t] = *(const float4a*)(xr + (2 + (t >> 1)) * 32 + (t & 1) * 4);

    STAGE(0, 0);
    __syncthreads();

    for (int p = 0; p < 16; ++p) {
        if (p < 15) STAGE(p + 1, (p + 1) & 1);
        float4 xn[4];
        if (p < 14) {
#pragma unroll
            for (int t = 0; t < 4; ++t)
                xn[t] = *(const float4a*)(xr + (2 * (p + 2) + (t >> 1)) * 32 + (t & 1) * 4);
        }
        const u16* wb = Wl[p & 1];
#pragma unroll
        for (int ccp = 0; ccp < 2; ++ccp) {
            short8 af = cvt8(xa[ccp * 2], xa[ccp * 2 + 1]);
#pragma unroll
            for (int mn = 0; mn < 12; ++mn) {
                short8 bf = *(const short8a*)(wb + ((size_t)(mn * 2 + ccp) * 64 + lane) * 8);
                acc[mn] = __builtin_amdgcn_mfma_f32_16x16x32_bf16(af, bf, acc[mn], 0, 0, 0);
            }
        }
#pragma unroll
        for (int t = 0; t < 4; ++t) { xa[t] = xb[t]; if (p < 14) xb[t] = xn[t]; }
        __syncthreads();
    }
#undef STAGE

    const int b  = (int)(rowbase >> 12);
    const int tb = (int)(rowbase & 4095);

    // q: natural [t][h]
#pragma unroll
    for (int n = 0; n < 4; ++n)
#pragma unroll
        for (int r = 0; r < 4; ++r)
            qb[(rowbase + quad * 4 + r) * 64 + n * 16 + m] = f2bf(acc[n][r]);

    // kA[b][key>>4][h>>5][(key&15)+16*((h>>3)&3)][h&7]
#pragma unroll
    for (int n = 0; n < 4; ++n) {
        int kk = n >> 1;
        int lq = (n * 2 + (m >> 3)) & 3;
        int j  = m & 7;
#pragma unroll
        for (int r = 0; r < 4; ++r) {
            int key = tb + quad * 4 + r;
            size_t a = ((((size_t)b * 256 + (key >> 4)) * 2 + kk) * 64
                        + ((key & 15) + 16 * lq)) * 8 + j;
            kA[a] = f2bf(acc[4 + n][r]);
        }
    }

    // vA[b][h>>4][key>>5][(h&15)+16*((key>>3)&3)][key&7]
    {
        int key0 = tb + quad * 4;
        int j0 = key0 & 7;
        int q2 = (key0 >> 3) & 3;
        int kc = key0 >> 5;
#pragma unroll
        for (int n = 0; n < 4; ++n) {
            u64 pv = (u64)pk_bf(acc[8 + n][0], acc[8 + n][1])
                   | ((u64)pk_bf(acc[8 + n][2], acc[8 + n][3]) << 32);
            size_t a = ((((size_t)b * 4 + n) * 128 + kc) * 64 + (m + 16 * q2)) * 8 + j0;
            *(u64a*)(vA + a) = pv;
        }
    }
}

// ---- attention: 32-row strips per wave (2 substrips share K/V regs), split-K ----
// Waves stay fully independent (no block barriers in K-loop). Each K/V register
// load now feeds 32 MFMA instead of 16 -> K/V L2 traffic halves. Both substrips
// of a 32-row strip share the same diagonal tile n_s = s32>>1, so one kt-walk
// serves both; per-lane key>qrow mask applied per substrip at kt==n_s.
struct K8 { short8 k[8]; };

__device__ __forceinline__ void loadK(K8& f, const u16* kAb, int kt, int lane) {
    const u16* kp = kAb + (size_t)kt * 4096 + (size_t)lane * 8;
#pragma unroll
    for (int mt = 0; mt < 4; ++mt) {
        f.k[mt * 2]     = *(const short8a*)(kp + mt * 1024);
        f.k[mt * 2 + 1] = *(const short8a*)(kp + mt * 1024 + 512);
    }
}

__device__ __forceinline__ void loadV(short8* vf, const u16* vAb, int kt, int lane) {
    const u16* vp = vAb + (size_t)kt * 1024 + (size_t)lane * 8;
#pragma unroll
    for (int ht = 0; ht < 4; ++ht) {
        vf[ht * 2]     = *(const short8a*)(vp + (size_t)ht * 65536);
        vf[ht * 2 + 1] = *(const short8a*)(vp + (size_t)ht * 65536 + 512);
    }
}

__device__ __forceinline__ void sub_step(const K8& f, const short8* vf,
        short8 qf0, short8 qf1, u16* pw,
        f32x4& o0, f32x4& o1, f32x4& o2, f32x4& o3,
        float& lsum, int kt, int n_s, int qrow, int quad, int m) {
    const float L2E = 1.4426950408889634f;
    const float FMB = 4.0f * L2E;
    f32x4 s[4];
    __builtin_amdgcn_s_setprio(1);
#pragma unroll
    for (int mt = 0; mt < 4; ++mt) {
        f32x4 a = (f32x4){0.f, 0.f, 0.f, 0.f};
        a = __builtin_amdgcn_mfma_f32_16x16x32_bf16(f.k[mt * 2],     qf0, a, 0, 0, 0);
        a = __builtin_amdgcn_mfma_f32_16x16x32_bf16(f.k[mt * 2 + 1], qf1, a, 0, 0, 0);
        s[mt] = a;
    }
    __builtin_amdgcn_s_setprio(0);
    if (kt == n_s) {
#pragma unroll
        for (int mt = 0; mt < 4; ++mt)
#pragma unroll
            for (int r = 0; r < 4; ++r) {
                int key = kt * 64 + mt * 16 + quad * 4 + r;
                if (key > qrow) s[mt][r] = -1e30f;
            }
    }
#pragma unroll
    for (int mt = 0; mt < 4; ++mt) {
        float p0 = __builtin_amdgcn_exp2f(s[mt][0] * L2E - FMB);
        float p1 = __builtin_amdgcn_exp2f(s[mt][1] * L2E - FMB);
        float p2 = __builtin_amdgcn_exp2f(s[mt][2] * L2E - FMB);
        float p3 = __builtin_amdgcn_exp2f(s[mt][3] * L2E - FMB);
        lsum += (p0 + p1) + (p2 + p3);
        u64 pv = (u64)pk_bf(p0, p1) | ((u64)pk_bf(p2, p3) << 32);
        *(u64a*)(pw + m * LPP + mt * 16 + quad * 4) = pv;
    }
    __builtin_amdgcn_wave_barrier();
    short8 pf0 = ld_frag_lds(pw + m * LPP + quad * 8);
    short8 pf1 = ld_frag_lds(pw + m * LPP + 32 + quad * 8);
    __builtin_amdgcn_s_setprio(1);
    o0 = __builtin_amdgcn_mfma_f32_16x16x32_bf16(vf[0], pf0, o0, 0, 0, 0);
    o0 = __builtin_amdgcn_mfma_f32_16x16x32_bf16(vf[1], pf1, o0, 0, 0, 0);
    o1 = __builtin_amdgcn_mfma_f32_16x16x32_bf16(vf[2], pf0, o1, 0, 0, 0);
    o1 = __builtin_amdgcn_mfma_f32_16x16x32_bf16(vf[3], pf1, o1, 0, 0, 0);
    o2 = __builtin_amdgcn_mfma_f32_16x16x32_bf16(vf[4], pf0, o2, 0, 0, 0);
    o2 = __builtin_amdgcn_mfma_f32_16x16x32_bf16(vf[5], pf1, o2, 0, 0, 0);
    o3 = __builtin_amdgcn_mfma_f32_16x16x32_bf16(vf[6], pf0, o3, 0, 0, 0);
    o3 = __builtin_amdgcn_mfma_f32_16x16x32_bf16(vf[7], pf1, o3, 0, 0, 0);
    __builtin_amdgcn_s_setprio(0);
}

__global__ __launch_bounds__(256, 2) void attn_kernel(const u16* __restrict__ qb,
                                                      const u16* __restrict__ kA,
                                                      const u16* __restrict__ vA,
                                                      float* __restrict__ out) {
    __shared__ __align__(16) u16 Pt[4][2][16 * LPP];
    __shared__ float Ob[4][2][16][64];
    __shared__ float Lb[4][2][64];

    const int tid = threadIdx.x, lane = tid & 63, wave = tid >> 6;
    const int m = lane & 15, quad = lane >> 4;
    const int beta = blockIdx.x;
    const int b = beta & 7, u = beta >> 3;            // u in [0,64)

    // 32-row strips: light s32=u (T0 tiles), heavy s32=127-u (T1); T0+T1 = 65
    const int T0 = (u >> 1) + 1;                      // in [1,32]
    const int T1 = 64 - (u >> 1);                     // in [33,64]
    // adaptive wave split: minimize max(ceil(T0/n0), ceil(T1/n1)) over {(1,3),(2,2)}
    const int max13 = (T0 > (T1 + 2) / 3) ? T0 : (T1 + 2) / 3;
    const int c22a = (T0 + 1) >> 1, c22b = (T1 + 1) >> 1;
    const int max22 = (c22a > c22b) ? c22a : c22b;
    const int n0 = (max13 <= max22) ? 1 : 2;
    const int n1 = 4 - n0;

    const int r = (wave + beta) & 3;                  // rotate roles across SIMDs
    const int strip_id = (r < n0) ? 0 : 1;
    const int part   = strip_id ? (r - n0) : r;
    const int nparts = strip_id ? n1 : n0;
    const int T      = strip_id ? T1 : T0;
    const int s32    = strip_id ? (127 - u) : u;      // 32-row strip index
    const int qbase = s32 * 32;
    const int n_s = s32 >> 1;                         // shared diagonal tile
    const int kt0 = part * T / nparts;
    const int kt1 = (part + 1) * T / nparts - 1;      // inclusive; last part ends at n_s

    const u16* qpA = qb + ((size_t)b * Tseq + qbase + m) * 64;
    const u16* qpB = qpA + 16 * 64;
    short8 qA0 = *(const short8a*)(qpA + quad * 8);
    short8 qA1 = *(const short8a*)(qpA + 32 + quad * 8);
    short8 qB0 = *(const short8a*)(qpB + quad * 8);
    short8 qB1 = *(const short8a*)(qpB + 32 + quad * 8);

    const u16* kAb = kA + (size_t)b * (256 * 2 * 64 * 8);
    const u16* vAb = vA + (size_t)b * (4 * 128 * 64 * 8);
    u16* pwA = Pt[wave][0];
    u16* pwB = Pt[wave][1];

    f32x4 oA0 = {0.f, 0.f, 0.f, 0.f}, oA1 = oA0, oA2 = oA0, oA3 = oA0;
    f32x4 oB0 = oA0, oB1 = oA0, oB2 = oA0, oB3 = oA0;
    float lsumA = 0.f, lsumB = 0.f;
    const int qrowA = qbase + m;
    const int qrowB = qbase + 16 + m;

    if (kt0 <= kt1) {
        K8 ka, kb2;
        short8 vf[8];
        loadK(ka, kAb, kt0, lane);
        int kt = kt0;
        while (true) {
            loadV(vf, vAb, kt, lane);                 // V first: needed sooner
            if (kt < kt1) loadK(kb2, kAb, kt + 1, lane);
            sub_step(ka, vf, qA0, qA1, pwA, oA0, oA1, oA2, oA3, lsumA,
                     kt, n_s, qrowA, quad, m);
            sub_step(ka, vf, qB0, qB1, pwB, oB0, oB1, oB2, oB3, lsumB,
                     kt, n_s, qrowB, quad, m);
            if (kt == kt1) break;
            ++kt;
            loadV(vf, vAb, kt, lane);
            if (kt < kt1) loadK(ka, kAb, kt + 1, lane);
            sub_step(kb2, vf, qA0, qA1, pwA, oA0, oA1, oA2, oA3, lsumA,
                     kt, n_s, qrowA, quad, m);
            sub_step(kb2, vf, qB0, qB1, pwB, oB0, oB1, oB2, oB3, lsumB,
                     kt, n_s, qrowB, quad, m);
            if (kt == kt1) break;
            ++kt;
        }
    }

    // merge parts: fixed-max softmax -> O and l add directly.
    // parts >= 1 publish both substrips to their role slot; part 0 accumulates.
    if (part != 0) {
        Ob[r][0][0][lane] = oA0[0]; Ob[r][0][1][lane] = oA0[1];
        Ob[r][0][2][lane] = oA0[2]; Ob[r][0][3][lane] = oA0[3];
        Ob[r][0][4][lane] = oA1[0]; Ob[r][0][5][lane] = oA1[1];
        Ob[r][0][6][lane] = oA1[2]; Ob[r][0][7][lane] = oA1[3];
        Ob[r][0][8][lane] = oA2[0]; Ob[r][0][9][lane] = oA2[1];
        Ob[r][0][10][lane] = oA2[2]; Ob[r][0][11][lane] = oA2[3];
        Ob[r][0][12][lane] = oA3[0]; Ob[r][0][13][lane] = oA3[1];
        Ob[r][0][14][lane] = oA3[2]; Ob[r][0][15][lane] = oA3[3];
        Lb[r][0][lane] = lsumA;
        Ob[r][1][0][lane] = oB0[0]; Ob[r][1][1][lane] = oB0[1];
        Ob[r][1][2][lane] = oB0[2]; Ob[r][1][3][lane] = oB0[3];
        Ob[r][1][4][lane] = oB1[0]; Ob[r][1][5][lane] = oB1[1];
        Ob[r][1][6][lane] = oB1[2]; Ob[r][1][7][lane] = oB1[3];
        Ob[r][1][8][lane] = oB2[0]; Ob[r][1][9][lane] = oB2[1];
        Ob[r][1][10][lane] = oB2[2]; Ob[r][1][11][lane] = oB2[3];
        Ob[r][1][12][lane] = oB3[0]; Ob[r][1][13][lane] = oB3[1];
        Ob[r][1][14][lane] = oB3[2]; Ob[r][1][15][lane] = oB3[3];
        Lb[r][1][lane] = lsumB;
    }
    __syncthreads();
    if (part == 0) {
#pragma unroll 1
        for (int pr = 1; pr < nparts; ++pr) {
            const int rr = r + pr;
            oA0[0] += Ob[rr][0][0][lane]; oA0[1] += Ob[rr][0][1][lane];
            oA0[2] += Ob[rr][0][2][lane]; oA0[3] += Ob[rr][0][3][lane];
            oA1[0] += Ob[rr][0][4][lane]; oA1[1] += Ob[rr][0][5][lane];
            oA1[2] += Ob[rr][0][6][lane]; oA1[3] += Ob[rr][0][7][lane];
            oA2[0] += Ob[rr][0][8][lane]; oA2[1] += Ob[rr][0][9][lane];
            oA2[2] += Ob[rr][0][10][lane]; oA2[3] += Ob[rr][0][11][lane];
            oA3[0] += Ob[rr][0][12][lane]; oA3[1] += Ob[rr][0][13][lane];
            oA3[2] += Ob[rr][0][14][lane]; oA3[3] += Ob[rr][0][15][lane];
            lsumA += Lb[rr][0][lane];
            oB0[0] += Ob[rr][1][0][lane]; oB0[1] += Ob[rr][1][1][lane];
            oB0[2] += Ob[rr][1][2][lane]; oB0[3] += Ob[rr][1][3][lane];
            oB1[0] += Ob[rr][1][4][lane]; oB1[1] += Ob[rr][1][5][lane];
            oB1[2] += Ob[rr][1][6][lane]; oB1[3] += Ob[rr][1][7][lane];
            oB2[0] += Ob[rr][1][8][lane]; oB2[1] += Ob[rr][1][9][lane];
            oB2[2] += Ob[rr][1][10][lane]; oB2[3] += Ob[rr][1][11][lane];
            oB3[0] += Ob[rr][1][12][lane]; oB3[1] += Ob[rr][1][13][lane];
            oB3[2] += Ob[rr][1][14][lane]; oB3[3] += Ob[rr][1][15][lane];
            lsumB += Lb[rr][1][lane];
        }

        lsumA += __shfl_xor(lsumA, 16, 64);
        lsumA += __shfl_xor(lsumA, 32, 64);
        lsumB += __shfl_xor(lsumB, 16, 64);
        lsumB += __shfl_xor(lsumB, 32, 64);
        float invA = 1.0f / lsumA;
        float invB = 1.0f / lsumB;

        float* orowA = out + ((size_t)b * Tseq + qbase + m) * 64;
        float* orowB = orowA + 16 * 64;
        float4 w;
        w.x = oA0[0] * invA; w.y = oA0[1] * invA; w.z = oA0[2] * invA; w.w = oA0[3] * invA;
        *(float4a*)(orowA + 0 * 16 + quad * 4) = w;
        w.x = oA1[0] * invA; w.y = oA1[1] * invA; w.z = oA1[2] * invA; w.w = oA1[3] * invA;
        *(float4a*)(orowA + 1 * 16 + quad * 4) = w;
        w.x = oA2[0] * invA; w.y = oA2[1] * invA; w.z = oA2[2] * invA; w.w = oA2[3] * invA;
        *(float4a*)(orowA + 2 * 16 + quad * 4) = w;
        w.x = oA3[0] * invA; w.y = oA3[1] * invA; w.z = oA3[2] * invA; w.w = oA3[3] * invA;
        *(float4a*)(orowA + 3 * 16 + quad * 4) = w;
        w.x = oB0[0] * invB; w.y = oB0[1] * invB; w.z = oB0[2] * invB; w.w = oB0[3] * invB;
        *(float4a*)(orowB + 0 * 16 + quad * 4) = w;
        w.x = oB1[0] * invB; w.y = oB1[1] * invB; w.z = oB1[2] * invB; w.w = oB1[3] * invB;
        *(float4a*)(orowB + 1 * 16 + quad * 4) = w;
        w.x = oB2[0] * invB; w.y = oB2[1] * invB; w.z = oB2[2] * invB; w.w = oB2[3] * invB;
        *(float4a*)(orowB + 2 * 16 + quad * 4) = w;
        w.x = oB3[0] * invB; w.y = oB3[1] * invB; w.z = oB3[2] * invB; w.w = oB3[3] * invB;
        *(float4a*)(orowB + 3 * 16 + quad * 4) = w;
    }
}

extern "C" void kernel_launch(void* const* d_in, const int* in_sizes, int n_in,
                              void* d_out, int out_size, void* d_ws, size_t ws_size,
                              hipStream_t stream) {
    const float* x  = (const float*)d_in[0];
    const float* Wq = (const float*)d_in[1];
    const float* Wk = (const float*)d_in[2];
    const float* Wv = (const float*)d_in[3];
    float* out = (float*)d_out;

    char* ws = (char*)d_ws;
    u16* wtf = (u16*)ws;                                       // 384 KiB
    u16* qb  = (u16*)(ws + 512 * 1024);                        // 4 MiB
    u16* kA  = (u16*)(ws + 512 * 1024 + 4 * 1024 * 1024);      // 4 MiB
    u16* vA  = (u16*)(ws + 512 * 1024 + 8 * 1024 * 1024);      // 4 MiB

    wt_kernel<<<96, 256, 0, stream>>>(Wq, Wk, Wv, wtf);
    proj_kernel<<<512, 256, 0, stream>>>(x, wtf, qb, kA, vA);
    attn_kernel<<<512, 256, 0, stream>>>(qb, kA, vA, out);
}